// Round 6
// baseline (305.491 us; speedup 1.0000x reference)
//
#include <hip/hip_runtime.h>
#include <math.h>

#define BB 4
#define SS 4096
#define DD 128
#define NSPK 9
#define WIN 15
#define EPSN 1e-8f
#define INV_PI 0.31830988618379067f

typedef float vfloat4 __attribute__((ext_vector_type(4)));

// ---------------------------------------------------------------------------
// k_band: COMPUTE ONLY. One wave handles TWO rows (32 lanes per row).
//   For row i, lane hl (0..30) handles neighbor j = i-15+hl:
//     - dot(x_i,x_j), ||x_j||^2 from raw x; ||x_i||^2 via shfl from hl==15
//     - w = 1 - acos(clamp(dot/(ni*nj)))/pi, masked by window & validity
//     - same-speaker doubling via per-half ballot popcount
//     - deg via half-wave butterfly; store band[row][hl] and dinv[row]
//   No output-array traffic: pure latency/compute kernel, L2-resident reads.
// ---------------------------------------------------------------------------
__global__ __launch_bounds__(256) void k_band(const float* __restrict__ x,
                                              const float* __restrict__ qmask,
                                              const int* __restrict__ dia_len,
                                              float* __restrict__ band,
                                              float* __restrict__ dinv) {
    int wid  = (blockIdx.x * blockDim.x + threadIdx.x) >> 6;   // 0..8191
    int lane = threadIdx.x & 63;
    int half = lane >> 5;          // 0: row A, 1: row B
    int hl   = lane & 31;

    int row = wid * 2 + half;      // 0..16383
    int b   = row >> 12;
    int i   = row & (SS - 1);
    int len = dia_len[b];

    int  j     = i - WIN + hl;                       // hl==31 -> out of band
    bool inr   = (hl < 31) && (j >= 0) && (j < SS);
    bool maskv = inr && (i < len) && (j < len);

    // speaker of column j (predicated, small cached table)
    int sj = 0;
    if (inr) {
        const float* q = qmask + ((size_t)j * BB + b) * NSPK;
        float best = q[0];
        #pragma unroll
        for (int k = 1; k < NSPK; ++k) {
            float qv = q[k];
            if (qv > best) { best = qv; sj = k; }    // first-max tie-break
        }
    }
    int si = __shfl(sj, (lane & 32) + WIN);          // lane where j == i
    bool same = inr && (sj == si);

    // dot(x_i, x_j) and ||x_j||^2 (predicated — R4-measured-faster style)
    float dot = 0.f, nj2 = 0.f;
    if (maskv) {
        const float4* xi = (const float4*)(x + (size_t)row * DD);
        const float4* xj = (const float4*)(x + ((size_t)b * SS + j) * DD);
        float d0 = 0.f, d1 = 0.f, n0 = 0.f, n1 = 0.f;
        #pragma unroll
        for (int d = 0; d < DD / 8; ++d) {
            float4 a0 = xi[2 * d],     c0 = xj[2 * d];
            float4 a1 = xi[2 * d + 1], c1 = xj[2 * d + 1];
            d0 += a0.x * c0.x + a0.y * c0.y + a0.z * c0.z + a0.w * c0.w;
            d1 += a1.x * c1.x + a1.y * c1.y + a1.z * c1.z + a1.w * c1.w;
            n0 += c0.x * c0.x + c0.y * c0.y + c0.z * c0.z + c0.w * c0.w;
            n1 += c1.x * c1.x + c1.y * c1.y + c1.z * c1.z + c1.w * c1.w;
        }
        dot = d0 + d1;
        nj2 = n0 + n1;
    }
    float ni2 = __shfl(nj2, (lane & 32) + WIN);      // ||x_i||^2 from j==i lane

    float aij = 0.f;
    if (maskv) {
        float ni = fmaxf(sqrtf(ni2), EPSN);
        float nj = fmaxf(sqrtf(nj2), EPSN);
        float c  = dot / (ni * nj);
        c = fminf(fmaxf(c, -1.f), 1.f);
        aij = 1.f - acosf(c) * INV_PI;
    }

    // same-speaker count inside window (per half), doubling
    unsigned long long bal = __ballot(maskv && same);
    unsigned long long hm  = half ? 0xFFFFFFFF00000000ull : 0x00000000FFFFFFFFull;
    int cnt = __popcll(bal & hm);
    if (maskv && same && cnt > 1) aij *= 2.f;

    // degree: butterfly within the 32-lane half
    float deg = aij;
    #pragma unroll
    for (int off = 16; off; off >>= 1) deg += __shfl_xor(deg, off);

    band[(size_t)row * 32 + hl] = aij;               // hl==31 writes 0
    if (hl == 0) {
        float dv = (deg == 0.f) ? 1.f : deg;
        dinv[row] = 1.0f / sqrtf(dv);
    }
}

// ---------------------------------------------------------------------------
// k_fill: PURE STREAMING WRITER. One wave per output row; writes the entire
// 4096-float row exactly once with NT float4 stores: zeros outside the band
// span, band*dinv_i*dinv_j inside. Should run at rocclr-fill BW (~6.4 TB/s).
// ---------------------------------------------------------------------------
__global__ __launch_bounds__(256) void k_fill(const float* __restrict__ band,
                                              const float* __restrict__ dinv,
                                              float* __restrict__ out) {
    int row  = (blockIdx.x * blockDim.x + threadIdx.x) >> 6;   // 0..16383
    int lane = threadIdx.x & 63;
    int b = row >> 12, i = row & (SS - 1);
    int j0 = i - WIN; if (j0 < 0) j0 = 0;
    int j1 = i + WIN; if (j1 > SS - 1) j1 = SS - 1;
    int fs = j0 >> 2, fe = j1 >> 2;

    float di = dinv[row];
    const float* brow = band + (size_t)row * 32;
    const float* dj   = dinv + (size_t)b * SS;
    vfloat4* orow = (vfloat4*)(out + (size_t)row * SS);

    #pragma unroll
    for (int it = 0; it < SS / 4 / 64; ++it) {       // 16 iterations
        int f = it * 64 + lane;
        vfloat4 v = (vfloat4)(0.f);
        if (f >= fs && f <= fe) {                    // ≤1 divergent iter/wave
            #pragma unroll
            for (int c = 0; c < 4; ++c) {
                int j = f * 4 + c;
                if (j >= j0 && j <= j1)
                    v[c] = brow[j - i + WIN] * di * dj[j];
            }
        }
        __builtin_nontemporal_store(v, orow + f);
    }
}

extern "C" void kernel_launch(void* const* d_in, const int* in_sizes, int n_in,
                              void* d_out, int out_size, void* d_ws, size_t ws_size,
                              hipStream_t stream) {
    const float* x       = (const float*)d_in[0];
    const float* qmask   = (const float*)d_in[1];
    const int*   dia_len = (const int*)d_in[2];
    float* out = (float*)d_out;

    char* ws = (char*)d_ws;
    const size_t rows = (size_t)BB * SS;
    float* band = (float*)ws;                        // rows*32 floats (2.1 MB)
    float* dinv = (float*)(ws + rows * 32 * 4);      // rows floats

    k_band<<<(int)(rows / 2 * 64 / 256), 256, 0, stream>>>(x, qmask, dia_len,
                                                           band, dinv);
    k_fill<<<(int)(rows * 64 / 256),     256, 0, stream>>>(band, dinv, out);
}

// Round 7
// 285.931 us; speedup vs baseline: 1.0684x; 1.0684x over previous
//
#include <hip/hip_runtime.h>
#include <math.h>

#define BB 4
#define SS 4096
#define DD 128
#define NSPK 9
#define WIN 15
#define EPSN 1e-8f
#define INV_PI 0.31830988618379067f

typedef float vfloat4 __attribute__((ext_vector_type(4)));

// ---------------------------------------------------------------------------
// k_main: one wave handles TWO rows (half-wave of 32 lanes per row).
//   COMPUTE (predicated, R4-style): for row i, lane hl in [0,31) handles
//   neighbor j = i-15+hl: dot/norms from raw x, w = 1-acos(cos)/pi, speaker
//   doubling via per-half ballot, deg via half-wave butterfly; store
//   band[row][hl], dinv[row].
//   FILL: all 64 lanes zero the non-band float4s of both rows (NT stores).
//   PHASE STAGGER: odd waves run FILL->COMPUTE, even waves COMPUTE->FILL,
//   so the HBM write pipe is saturated from t=0 while compute hides under
//   other waves' store streams (and vmcnt FIFO never blocks a load that is
//   needed before that wave's own stores).
// ---------------------------------------------------------------------------
__global__ __launch_bounds__(256) void k_main(const float* __restrict__ x,
                                              const float* __restrict__ qmask,
                                              const int* __restrict__ dia_len,
                                              float* __restrict__ band,
                                              float* __restrict__ dinv,
                                              float* __restrict__ out) {
    int wid  = (blockIdx.x * blockDim.x + threadIdx.x) >> 6;   // 0..8191
    int lane = threadIdx.x & 63;
    int rA = wid * 2, rB = rA + 1;

    auto FILL = [&]() {
        int iA = rA & (SS - 1), iB = rB & (SS - 1);
        int fsA = (iA - WIN < 0 ? 0 : iA - WIN) >> 2;
        int feA = (iA + WIN > SS - 1 ? SS - 1 : iA + WIN) >> 2;
        int fsB = (iB - WIN < 0 ? 0 : iB - WIN) >> 2;
        int feB = (iB + WIN > SS - 1 ? SS - 1 : iB + WIN) >> 2;
        vfloat4 z = (vfloat4)(0.f);
        vfloat4* oA = (vfloat4*)(out + (size_t)rA * SS);
        vfloat4* oB = (vfloat4*)(out + (size_t)rB * SS);
        #pragma unroll
        for (int it = 0; it < SS / 4 / 64; ++it) {   // 16 iterations
            int f = it * 64 + lane;
            if (f < fsA || f > feA) __builtin_nontemporal_store(z, oA + f);
            if (f < fsB || f > feB) __builtin_nontemporal_store(z, oB + f);
        }
    };

    auto COMPUTE = [&]() {
        int half = lane >> 5;          // 0: row A, 1: row B
        int hl   = lane & 31;
        int row  = rA + half;
        int b    = row >> 12;
        int i    = row & (SS - 1);
        int len  = dia_len[b];

        int  j     = i - WIN + hl;                   // hl==31 -> out of band
        bool inr   = (hl < 31) && (j >= 0) && (j < SS);
        bool maskv = inr && (i < len) && (j < len);

        int sj = 0;
        if (inr) {
            const float* q = qmask + ((size_t)j * BB + b) * NSPK;
            float best = q[0];
            #pragma unroll
            for (int k = 1; k < NSPK; ++k) {
                float qv = q[k];
                if (qv > best) { best = qv; sj = k; }  // first-max tie-break
            }
        }
        int si = __shfl(sj, (lane & 32) + WIN);      // lane where j == i
        bool same = inr && (sj == si);

        float dot = 0.f, nj2 = 0.f;
        if (maskv) {
            const float4* xi = (const float4*)(x + (size_t)row * DD);
            const float4* xj = (const float4*)(x + ((size_t)(b << 12) + j) * DD);
            float d0 = 0.f, d1 = 0.f, n0 = 0.f, n1 = 0.f;
            #pragma unroll
            for (int d = 0; d < DD / 8; ++d) {
                float4 a0 = xi[2 * d],     c0 = xj[2 * d];
                float4 a1 = xi[2 * d + 1], c1 = xj[2 * d + 1];
                d0 += a0.x * c0.x + a0.y * c0.y + a0.z * c0.z + a0.w * c0.w;
                d1 += a1.x * c1.x + a1.y * c1.y + a1.z * c1.z + a1.w * c1.w;
                n0 += c0.x * c0.x + c0.y * c0.y + c0.z * c0.z + c0.w * c0.w;
                n1 += c1.x * c1.x + c1.y * c1.y + c1.z * c1.z + c1.w * c1.w;
            }
            dot = d0 + d1;
            nj2 = n0 + n1;
        }
        float ni2 = __shfl(nj2, (lane & 32) + WIN);  // ||x_i||^2 from j==i lane

        float aij = 0.f;
        if (maskv) {
            float ni = fmaxf(sqrtf(ni2), EPSN);
            float nj = fmaxf(sqrtf(nj2), EPSN);
            float c  = dot / (ni * nj);
            c = fminf(fmaxf(c, -1.f), 1.f);
            aij = 1.f - acosf(c) * INV_PI;
        }

        unsigned long long bal = __ballot(maskv && same);
        unsigned long long hm  = half ? 0xFFFFFFFF00000000ull
                                      : 0x00000000FFFFFFFFull;
        int cnt = __popcll(bal & hm);
        if (maskv && same && cnt > 1) aij *= 2.f;

        float deg = aij;
        #pragma unroll
        for (int off = 16; off; off >>= 1) deg += __shfl_xor(deg, off);

        band[(size_t)row * 32 + hl] = aij;           // hl==31 writes 0
        if (hl == 0) {
            float dv = (deg == 0.f) ? 1.f : deg;
            dinv[row] = 1.0f / sqrtf(dv);
        }
    };

    if (wid & 1) { FILL(); COMPUTE(); }
    else         { COMPUTE(); FILL(); }
}

// ---------------------------------------------------------------------------
// k_bw: one wave per row; writes ONLY the band-region float4s (the ones
// k_main skipped), scaled by dinv_i * dinv_j. ~2.4 MB total.
// ---------------------------------------------------------------------------
__global__ __launch_bounds__(256) void k_bw(const float* __restrict__ band,
                                            const float* __restrict__ dinv,
                                            float* __restrict__ out) {
    int row  = (blockIdx.x * blockDim.x + threadIdx.x) >> 6;
    int lane = threadIdx.x & 63;
    if (row >= BB * SS) return;
    int b = row >> 12, i = row & (SS - 1);
    int j0 = i - WIN; if (j0 < 0) j0 = 0;
    int j1 = i + WIN; if (j1 > SS - 1) j1 = SS - 1;
    int fs = j0 >> 2, fe = j1 >> 2;

    int j = fs * 4 + lane;                           // covers [fs*4, fe*4+3]
    if (j > fe * 4 + 3) return;

    float v = 0.f;
    if (j >= j0 && j <= j1) {
        v = band[(size_t)row * 32 + (j - i + WIN)] * dinv[row] * dinv[b * SS + j];
    }
    __builtin_nontemporal_store(v, out + (size_t)row * SS + j);
}

extern "C" void kernel_launch(void* const* d_in, const int* in_sizes, int n_in,
                              void* d_out, int out_size, void* d_ws, size_t ws_size,
                              hipStream_t stream) {
    const float* x       = (const float*)d_in[0];
    const float* qmask   = (const float*)d_in[1];
    const int*   dia_len = (const int*)d_in[2];
    float* out = (float*)d_out;

    char* ws = (char*)d_ws;
    const size_t rows = (size_t)BB * SS;
    float* band = (float*)ws;                        // rows*32 floats (2.1 MB)
    float* dinv = (float*)(ws + rows * 32 * 4);      // rows floats

    k_main<<<(int)(rows / 2 * 64 / 256), 256, 0, stream>>>(x, qmask, dia_len,
                                                           band, dinv, out);
    k_bw  <<<(int)(rows * 64 / 256),     256, 0, stream>>>(band, dinv, out);
}

// Round 8
// 284.618 us; speedup vs baseline: 1.0733x; 1.0046x over previous
//
#include <hip/hip_runtime.h>
#include <math.h>

#define BB 4
#define SS 4096
#define DD 128
#define NSPK 9
#define WIN 15
#define EPSN 1e-8f
#define INV_PI 0.31830988618379067f

typedef float vfloat4 __attribute__((ext_vector_type(4)));

// ---------------------------------------------------------------------------
// k_main: WAVE ROLE-SPLIT. 16384 waves; pair p = wid>>1 owns rows 2p, 2p+1.
//   wid even -> FILL: pure NT zero-stores of the non-band float4s of both
//     rows. No loads => no s_waitcnt ever blocks the store stream.
//   wid odd  -> COMPUTE: R7's predicated band compute for the same two rows
//     (32 lanes per row). No out-stores => loads never queue behind stores.
//   Roles interleave per-wave so both populations co-reside on every SIMD:
//   the HBM write pipe is saturated from t=0, compute latency hides under it.
// ---------------------------------------------------------------------------
__global__ __launch_bounds__(256) void k_main(const float* __restrict__ x,
                                              const float* __restrict__ qmask,
                                              const int* __restrict__ dia_len,
                                              float* __restrict__ band,
                                              float* __restrict__ dinv,
                                              float* __restrict__ out) {
    int wid  = (blockIdx.x * blockDim.x + threadIdx.x) >> 6;   // 0..16383
    int lane = threadIdx.x & 63;
    int p    = wid >> 1;
    int rA = p * 2, rB = rA + 1;

    if (!(wid & 1)) {
        // ---------------- FILL role: store-only wave ----------------
        int iA = rA & (SS - 1), iB = rB & (SS - 1);
        int fsA = (iA - WIN < 0 ? 0 : iA - WIN) >> 2;
        int feA = (iA + WIN > SS - 1 ? SS - 1 : iA + WIN) >> 2;
        int fsB = (iB - WIN < 0 ? 0 : iB - WIN) >> 2;
        int feB = (iB + WIN > SS - 1 ? SS - 1 : iB + WIN) >> 2;
        vfloat4 z = (vfloat4)(0.f);
        vfloat4* oA = (vfloat4*)(out + (size_t)rA * SS);
        vfloat4* oB = (vfloat4*)(out + (size_t)rB * SS);
        #pragma unroll
        for (int it = 0; it < SS / 4 / 64; ++it) {   // 16 iterations
            int f = it * 64 + lane;
            if (f < fsA || f > feA) __builtin_nontemporal_store(z, oA + f);
            if (f < fsB || f > feB) __builtin_nontemporal_store(z, oB + f);
        }
        return;
    }

    // ---------------- COMPUTE role: load/VALU-only wave ----------------
    int half = lane >> 5;          // 0: row A, 1: row B
    int hl   = lane & 31;
    int row  = rA + half;
    int b    = row >> 12;
    int i    = row & (SS - 1);
    int len  = dia_len[b];

    int  j     = i - WIN + hl;                       // hl==31 -> out of band
    bool inr   = (hl < 31) && (j >= 0) && (j < SS);
    bool maskv = inr && (i < len) && (j < len);

    int sj = 0;
    if (inr) {
        const float* q = qmask + ((size_t)j * BB + b) * NSPK;
        float best = q[0];
        #pragma unroll
        for (int k = 1; k < NSPK; ++k) {
            float qv = q[k];
            if (qv > best) { best = qv; sj = k; }    // first-max tie-break
        }
    }
    int si = __shfl(sj, (lane & 32) + WIN);          // lane where j == i
    bool same = inr && (sj == si);

    float dot = 0.f, nj2 = 0.f;
    if (maskv) {
        const float4* xi = (const float4*)(x + (size_t)row * DD);
        const float4* xj = (const float4*)(x + ((size_t)(b << 12) + j) * DD);
        float d0 = 0.f, d1 = 0.f, n0 = 0.f, n1 = 0.f;
        #pragma unroll
        for (int d = 0; d < DD / 8; ++d) {
            float4 a0 = xi[2 * d],     c0 = xj[2 * d];
            float4 a1 = xi[2 * d + 1], c1 = xj[2 * d + 1];
            d0 += a0.x * c0.x + a0.y * c0.y + a0.z * c0.z + a0.w * c0.w;
            d1 += a1.x * c1.x + a1.y * c1.y + a1.z * c1.z + a1.w * c1.w;
            n0 += c0.x * c0.x + c0.y * c0.y + c0.z * c0.z + c0.w * c0.w;
            n1 += c1.x * c1.x + c1.y * c1.y + c1.z * c1.z + c1.w * c1.w;
        }
        dot = d0 + d1;
        nj2 = n0 + n1;
    }
    float ni2 = __shfl(nj2, (lane & 32) + WIN);      // ||x_i||^2 from j==i lane

    float aij = 0.f;
    if (maskv) {
        float ni = fmaxf(sqrtf(ni2), EPSN);
        float nj = fmaxf(sqrtf(nj2), EPSN);
        float c  = dot / (ni * nj);
        c = fminf(fmaxf(c, -1.f), 1.f);
        aij = 1.f - acosf(c) * INV_PI;
    }

    unsigned long long bal = __ballot(maskv && same);
    unsigned long long hm  = half ? 0xFFFFFFFF00000000ull
                                  : 0x00000000FFFFFFFFull;
    int cnt = __popcll(bal & hm);
    if (maskv && same && cnt > 1) aij *= 2.f;

    float deg = aij;
    #pragma unroll
    for (int off = 16; off; off >>= 1) deg += __shfl_xor(deg, off);

    band[(size_t)row * 32 + hl] = aij;               // hl==31 writes 0
    if (hl == 0) {
        float dv = (deg == 0.f) ? 1.f : deg;
        dinv[row] = 1.0f / sqrtf(dv);
    }
}

// ---------------------------------------------------------------------------
// k_bw: one wave per row; writes ONLY the band-region float4s (the ones
// k_main's fill skipped), scaled by dinv_i * dinv_j. ~2.4 MB total.
// ---------------------------------------------------------------------------
__global__ __launch_bounds__(256) void k_bw(const float* __restrict__ band,
                                            const float* __restrict__ dinv,
                                            float* __restrict__ out) {
    int row  = (blockIdx.x * blockDim.x + threadIdx.x) >> 6;
    int lane = threadIdx.x & 63;
    if (row >= BB * SS) return;
    int b = row >> 12, i = row & (SS - 1);
    int j0 = i - WIN; if (j0 < 0) j0 = 0;
    int j1 = i + WIN; if (j1 > SS - 1) j1 = SS - 1;
    int fs = j0 >> 2, fe = j1 >> 2;

    int j = fs * 4 + lane;                           // covers [fs*4, fe*4+3]
    if (j > fe * 4 + 3) return;

    float v = 0.f;
    if (j >= j0 && j <= j1) {
        v = band[(size_t)row * 32 + (j - i + WIN)] * dinv[row] * dinv[b * SS + j];
    }
    __builtin_nontemporal_store(v, out + (size_t)row * SS + j);
}

extern "C" void kernel_launch(void* const* d_in, const int* in_sizes, int n_in,
                              void* d_out, int out_size, void* d_ws, size_t ws_size,
                              hipStream_t stream) {
    const float* x       = (const float*)d_in[0];
    const float* qmask   = (const float*)d_in[1];
    const int*   dia_len = (const int*)d_in[2];
    float* out = (float*)d_out;

    char* ws = (char*)d_ws;
    const size_t rows = (size_t)BB * SS;
    float* band = (float*)ws;                        // rows*32 floats (2.1 MB)
    float* dinv = (float*)(ws + rows * 32 * 4);      // rows floats

    // 16384 waves: even = fill (2 rows), odd = compute (2 rows)
    k_main<<<(int)(rows * 64 / 256), 256, 0, stream>>>(x, qmask, dia_len,
                                                       band, dinv, out);
    k_bw  <<<(int)(rows * 64 / 256), 256, 0, stream>>>(band, dinv, out);
}